// Round 10
// baseline (258.947 us; speedup 1.0000x reference)
//
#include <hip/hip_runtime.h>
#include <hip/hip_bf16.h>

#define N_PTS 262144
#define STEP_LEN 0.0016914558667664818f

using f32x4 = __attribute__((ext_vector_type(4))) float;
using f32x16 = __attribute__((ext_vector_type(16))) float;
using s8 = __attribute__((ext_vector_type(8))) short;

__device__ __forceinline__ float bf2f(short s) {
    union { unsigned int u; float f; } v;
    v.u = ((unsigned int)(unsigned short)s) << 16;
    return v.f;
}
__device__ __forceinline__ short f2bf(float f) {
    __hip_bfloat16 h = __float2bfloat16(f);
    return *reinterpret_cast<short*>(&h);
}

// ---- workspace: 32x32x16 fragment order ----
// Trunk hidden blocks: [kc16][nt8][lane][8]; n = nt*32 + (lane&31), h = lane>>5
//   hidden f-map (acc->B):  f = kc*16 + (j>>2)*8 + h*4 + (j&3)
//   pe-input  f-map (ident): f = kc*16 + h*8 + j
// Consumed as 32KB pairs (pair p = bytes [p*32768, +32768)). Same offsets as r9.
#define OFF_W1    0         // 4 kc (pe)           = pair 0
#define OFF_L1H0  16384     // 3 x 16 kc           = pairs 1-12
#define OFF_W2    212992    // 20 kc (16 hid+4 pe) = pairs 13-17
#define OFF_L2H0  294912    // 3 x 16 kc           = pairs 18-29
#define OFF_C1G   491520    // [16kc][4nt][lane][8]= pairs 30-31
#define OFF_C1DE  524288    // [2kc][4nt][lane][8] = 8KB
#define OFF_WSIG  528384    // [16kc][2h][8j]
#define OFF_WC2   528640    // [3ch][4nt][2h][16r]
#define WS_ELEMS  532480

__global__ void prep_weights(const float* __restrict__ w1_in,
                             const float* __restrict__ w1_h,
                             const float* __restrict__ w2_in,
                             const float* __restrict__ w2_h,
                             const float* __restrict__ w_c1,
                             const float* __restrict__ w_sigma,
                             const float* __restrict__ w_c2,
                             __hip_bfloat16* __restrict__ ws) {
    int i = blockIdx.x * blockDim.x + threadIdx.x;
    if (i >= WS_ELEMS) return;
    float v;
    if (i < OFF_L1H0) {              // W1: pe input, identity f-map
        int e = i;
        int j = e & 7, lane = (e >> 3) & 63, nt = (e >> 9) & 7, kc = e >> 12;
        int n = nt * 32 + (lane & 31), h = lane >> 5;
        int f = kc * 16 + h * 8 + j;
        v = (f < 63) ? w1_in[n * 63 + f] : 0.f;
    } else if (i < OFF_W2) {         // 3x L1 hidden, permuted f-map
        int e = i - OFF_L1H0; int sub = e >> 16; e &= 65535;
        int j = e & 7, lane = (e >> 3) & 63, nt = (e >> 9) & 7, kc = e >> 12;
        int n = nt * 32 + (lane & 31), h = lane >> 5;
        int f = kc * 16 + ((j >> 2) << 3) + h * 4 + (j & 3);
        v = w1_h[sub * 65536 + n * 256 + f];
    } else if (i < OFF_L2H0) {       // W2: 16 hidden kc + 4 pe kc
        int e = i - OFF_W2;
        int j = e & 7, lane = (e >> 3) & 63, nt = (e >> 9) & 7, kc = e >> 12;
        int n = nt * 32 + (lane & 31), h = lane >> 5;
        if (kc < 16) {
            int f = kc * 16 + ((j >> 2) << 3) + h * 4 + (j & 3);
            v = w2_in[n * 319 + f];
        } else {
            int pf = (kc - 16) * 16 + h * 8 + j;
            v = (pf < 63) ? w2_in[n * 319 + 256 + pf] : 0.f;
        }
    } else if (i < OFF_C1G) {        // 3x L2 hidden
        int e = i - OFF_L2H0; int sub = e >> 16; e &= 65535;
        int j = e & 7, lane = (e >> 3) & 63, nt = (e >> 9) & 7, kc = e >> 12;
        int n = nt * 32 + (lane & 31), h = lane >> 5;
        int f = kc * 16 + ((j >> 2) << 3) + h * 4 + (j & 3);
        v = w2_h[sub * 65536 + n * 256 + f];
    } else if (i < OFF_C1DE) {       // color1 g-part: [16kc][4nt][lane][8]
        int e = i - OFF_C1G;
        int j = e & 7, lane = (e >> 3) & 63, nt = (e >> 9) & 3, kc = e >> 11;
        int n = nt * 32 + (lane & 31), h = lane >> 5;
        int f = kc * 16 + ((j >> 2) << 3) + h * 4 + (j & 3);
        v = w_c1[n * 283 + f];
    } else if (i < OFF_WSIG) {       // color1 de-part: identity f-map
        int e = i - OFF_C1DE;
        int j = e & 7, lane = (e >> 3) & 63, nt = (e >> 9) & 3, kc = e >> 11;
        int n = nt * 32 + (lane & 31), h = lane >> 5;
        int k = 256 + kc * 16 + h * 8 + j;
        v = (k < 283) ? w_c1[n * 283 + k] : 0.f;
    } else if (i < OFF_WC2) {        // sigma weights, permuted f-map
        int e = i - OFF_WSIG;
        int j = e & 7, h = (e >> 3) & 1, kc = e >> 4;
        int f = kc * 16 + ((j >> 2) << 3) + h * 4 + (j & 3);
        v = w_sigma[f];
    } else if (i < 529024) {         // color2: [3ch][4nt][2h][16r], n via C/D map
        int e = i - OFF_WC2;
        int r = e & 15, h = (e >> 4) & 1, nt = (e >> 5) & 3, ch = e >> 7;
        int n = nt * 32 + (r & 3) + 8 * (r >> 2) + 4 * h;
        v = w_c2[ch * 128 + n];
    } else {
        v = 0.f;
    }
    ws[i] = __float2bfloat16(v);
}

__device__ __forceinline__ float enc3(int f, float x0, float x1, float x2) {
    if (f < 3) return (f == 0) ? x0 : ((f == 1) ? x1 : x2);
    if (f < 33) {
        int q = f - 3; int c = q / 10, o = q % 10;
        float xc = (c == 0) ? x0 : ((c == 1) ? x1 : x2);
        return __sinf(xc * (float)(1 << o));
    }
    if (f < 63) {
        int q = f - 33; int c = q / 10, o = q % 10;
        float xc = (c == 0) ? x0 : ((c == 1) ? x1 : x2);
        return __cosf(xc * (float)(1 << o));
    }
    return 0.f;
}

#define MFMA32 __builtin_amdgcn_mfma_f32_32x32x16_bf16

#define GLL(SRC, DST) __builtin_amdgcn_global_load_lds( \
    (const unsigned int*)(SRC), (unsigned int*)(DST), 16, 0, 0)

// stage one 32KB pair: 4 waves x 8 x 1KB
#define STAGE8(BYTEOFF, DBUF) do { \
    const char* _src = wsB + (long)(BYTEOFF) + wid * 8192 + lane * 16; \
    char* _dst = (DBUF) + wid * 8192; \
    GLL(_src,        _dst);        GLL(_src + 1024, _dst + 1024); \
    GLL(_src + 2048, _dst + 2048); GLL(_src + 3072, _dst + 3072); \
    GLL(_src + 4096, _dst + 4096); GLL(_src + 5120, _dst + 5120); \
    GLL(_src + 6144, _dst + 6144); GLL(_src + 7168, _dst + 7168); \
} while (0)

#define SP1 __builtin_amdgcn_s_setprio(1)
#define SP0 __builtin_amdgcn_s_setprio(0)

// one trunk pair: 4 kc x 8 nt (act source)
#define WPAIR_A(RD, KC, FIRSTV) do { \
    _Pragma("unroll") \
    for (int kc2 = 0; kc2 < 4; ++kc2) { \
        _Pragma("unroll") \
        for (int nt = 0; nt < 8; ++nt) { \
            const s8 w = *(const s8*)((RD) + (kc2 * 8 + nt) * 1024 + lane * 16); \
            acc[nt] = MFMA32(w, act[(KC) + kc2], \
                             ((FIRSTV) && kc2 == 0) ? Z : acc[nt], 0, 0, 0); \
        } } } while (0)

// one trunk pair: 4 kc x 8 nt (pe source)
#define WPAIR_P(RD, FIRSTV) do { \
    _Pragma("unroll") \
    for (int kc2 = 0; kc2 < 4; ++kc2) { \
        _Pragma("unroll") \
        for (int nt = 0; nt < 8; ++nt) { \
            const s8 w = *(const s8*)((RD) + (kc2 * 8 + nt) * 1024 + lane * 16); \
            acc[nt] = MFMA32(w, pe[kc2], \
                             ((FIRSTV) && kc2 == 0) ? Z : acc[nt], 0, 0, 0); \
        } } } while (0)

// one color pair: 8 kc x 4 nt
#define CPAIR(RD, KC, FIRSTV) do { \
    _Pragma("unroll") \
    for (int kc2 = 0; kc2 < 8; ++kc2) { \
        _Pragma("unroll") \
        for (int nt = 0; nt < 4; ++nt) { \
            const s8 w = *(const s8*)((RD) + (kc2 * 4 + nt) * 1024 + lane * 16); \
            acc[nt] = MFMA32(w, act[(KC) + kc2], \
                             ((FIRSTV) && kc2 == 0) ? Z : acc[nt], 0, 0, 0); \
        } } } while (0)

// pair barrier: stage loads issued a full pair (~2300+ cyc) ago
#define PBAR do { asm volatile("s_waitcnt vmcnt(0)" ::: "memory"); \
                  __builtin_amdgcn_s_barrier(); } while (0)

// acc[8][16] -> act[16] chunks: chunk = nt*2 + (q>>1), j = (q&1)*4 + i, r = q*4+i
#define CONVERTL(BOFF) do { \
    _Pragma("unroll") \
    for (int nt = 0; nt < 8; ++nt) { \
        _Pragma("unroll") \
        for (int q = 0; q < 4; ++q) { \
            const f32x4 b4 = *(const f32x4*)(biasL + (((BOFF) + nt * 32 + q * 8 + h4) << 2)); \
            _Pragma("unroll") \
            for (int i2 = 0; i2 < 4; ++i2) { \
                float x = fmaxf(acc[nt][q * 4 + i2] + b4[i2], 0.f); \
                act[nt * 2 + (q >> 1)][((q & 1) << 2) | i2] = f2bf(x); \
            } } } } while (0)

// one hidden layer = 4 pairs starting at pair P; X = buf(P&1), Y = other
#define LAYER4(P, X, Y, BO) do { \
    STAGE8((long)((P) + 1) * 32768, Y); SP1; WPAIR_A(X, 0, 1);  SP0; PBAR; \
    STAGE8((long)((P) + 2) * 32768, X); SP1; WPAIR_A(Y, 4, 0);  SP0; PBAR; \
    STAGE8((long)((P) + 3) * 32768, Y); SP1; WPAIR_A(X, 8, 0);  SP0; PBAR; \
    STAGE8((long)((P) + 4) * 32768, X); SP1; WPAIR_A(Y, 12, 0); SP0; \
    CONVERTL(BO); PBAR; \
} while (0)

__global__ __launch_bounds__(256, 2) void nerf_fused(
    const float* __restrict__ pos, const float* __restrict__ dir,
    const __hip_bfloat16* __restrict__ ws,
    const float* __restrict__ b1_in, const float* __restrict__ b1_h,
    const float* __restrict__ b2_in, const float* __restrict__ b2_h,
    const float* __restrict__ b_sigma, const float* __restrict__ b_c1,
    const float* __restrict__ b_c2,
    float* __restrict__ out) {

    // 2 x 32KB weight ping-pong + 8.7KB bias table = 74.2KB -> 2 blocks/CU
    __shared__ __align__(16) char Lds[74240];
    char* const B0 = Lds;
    char* const B1 = Lds + 32768;
    char* const biasL = Lds + 65536;

    const int t = threadIdx.x;
    const int lane = t & 63;
    const int wid = t >> 6;
    const int h = lane >> 5;          // k-half
    const int h4 = h * 4;
    const int h8 = h * 8;
    const int h16 = h * 16;
    const int row0 = blockIdx.x * 128;
    const int g = row0 + wid * 32 + (lane & 31);   // this lane's point
    const char* wsB = (const char*)ws;

    // ---- stage pair 0 first (latency covered by prologue VALU work) ----
    STAGE8(0L, B0);

    // ---- biases -> LDS (f32): [b1_in|b1_h*3|b2_in|b2_h*3|b_c1] ----
    for (int i = t; i < 2176; i += 256) {
        float v;
        if (i < 256) v = b1_in[i];
        else if (i < 1024) v = b1_h[i - 256];
        else if (i < 1280) v = b2_in[i - 1024];
        else if (i < 2048) v = b2_h[i - 1280];
        else v = b_c1[i - 2048];
        *(float*)(biasL + i * 4) = v;
    }

    // ---- positional encoding frags (identity f-map: f = kc*16 + h*8 + j) ----
    s8 pe[4];
    {
        float x0 = pos[g * 3], x1 = pos[g * 3 + 1], x2 = pos[g * 3 + 2];
#pragma unroll
        for (int kc = 0; kc < 4; ++kc)
#pragma unroll
            for (int j = 0; j < 8; ++j)
                pe[kc][j] = f2bf(enc3(kc * 16 + h8 + j, x0, x1, x2));
    }

    // ---- dir-encoding frags EARLY (d = dc*16 + h*8 + j; sigma patched later) ----
    s8 de[2];
    {
        float u0 = (dir[g * 3 + 0] + 1.f) * 0.5f;
        float u1 = (dir[g * 3 + 1] + 1.f) * 0.5f;
        float u2 = (dir[g * 3 + 2] + 1.f) * 0.5f;
#pragma unroll
        for (int dc = 0; dc < 2; ++dc)
#pragma unroll
            for (int j = 0; j < 8; ++j) {
                int d = dc * 16 + h8 + j;
                float v = 0.f;
                if (d < 13) {
                    int c = d / 5, o = d % 5;
                    v = __sinf(((c == 0) ? u0 : (c == 1) ? u1 : u2) * (float)(1 << o));
                } else if (d < 26) {
                    int q = d - 13; int c = q / 5, o = q % 5;
                    v = __cosf(((c == 0) ? u0 : (c == 1) ? u1 : u2) * (float)(1 << o));
                }
                de[dc][j] = f2bf(v);
            }
    }

    f32x16 acc[8];
    s8 act[16];
    const f32x16 Z = {0.f, 0.f, 0.f, 0.f, 0.f, 0.f, 0.f, 0.f,
                      0.f, 0.f, 0.f, 0.f, 0.f, 0.f, 0.f, 0.f};

    // ---- prologue barrier: pair 0 landed + bias table visible ----
    asm volatile("s_waitcnt vmcnt(0) lgkmcnt(0)" ::: "memory");
    __builtin_amdgcn_s_barrier();

    // ---- pair 0: W1 (K=64 from pe) ----
    STAGE8(1L * 32768, B1);
    SP1; WPAIR_P(B0, 1); SP0;
    CONVERTL(0); PBAR;

    // ---- 3x L1 hidden: pairs 1-12 ----
    LAYER4(1, B1, B0, 256);
    LAYER4(5, B1, B0, 512);
    LAYER4(9, B1, B0, 768);

    // ---- W2: pairs 13-17 (16 act kc + 4 pe kc) ----
    STAGE8(14L * 32768, B0); SP1; WPAIR_A(B1, 0, 1);  SP0; PBAR;
    STAGE8(15L * 32768, B1); SP1; WPAIR_A(B0, 4, 0);  SP0; PBAR;
    STAGE8(16L * 32768, B0); SP1; WPAIR_A(B1, 8, 0);  SP0; PBAR;
    STAGE8(17L * 32768, B1); SP1; WPAIR_A(B0, 12, 0); SP0; PBAR;
    STAGE8(18L * 32768, B0); SP1; WPAIR_P(B1, 0);     SP0;
    CONVERTL(1024); PBAR;

    // ---- 3x L2 hidden: pairs 18-29 ----
    LAYER4(18, B0, B1, 1280);
    LAYER4(22, B0, B1, 1536);
    LAYER4(26, B0, B1, 1792);
    // g in act[0..15]. Pair 30 (C1G kc0-7) landed in B0.

    // ---- pair 30: stage 31; sigma head overlaps; color1 kc0-7 ----
    STAGE8(31L * 32768, B1);
    float sr, alpha;
    {
        float s = 0.f;
#pragma unroll
        for (int kc = 0; kc < 16; ++kc) {
            const s8 wv = *(const s8*)(wsB + (OFF_WSIG + kc * 16 + h8) * 2);
#pragma unroll
            for (int j = 0; j < 8; ++j)
                s += bf2f(act[kc][j]) * bf2f(wv[j]);
        }
        s += __shfl_xor(s, 32);
        sr = s + b_sigma[0];
        alpha = 1.f - __expf(-fmaxf(sr, 0.f) * STEP_LEN);
        if (lane >= 32) de[1][2] = f2bf(sr);   // d=26 lives at h=1, dc=1, j=2
    }
    SP1; CPAIR(B0, 0, 1); SP0; PBAR;

    // ---- pair 31: color1 kc8-15; stage C1DE (8KB) into B0 ----
    {
        const char* _src = wsB + 1048576L + wid * 2048 + lane * 16;
        char* _dst = B0 + wid * 2048;
        GLL(_src, _dst); GLL(_src + 1024, _dst + 1024);
    }
    SP1; CPAIR(B1, 8, 0); SP0; PBAR;

    // ---- de part of color1 from B0 (2 kc x 4 nt) ----
    SP1;
#pragma unroll
    for (int kc2 = 0; kc2 < 2; ++kc2)
#pragma unroll
        for (int nt = 0; nt < 4; ++nt) {
            const s8 w = *(const s8*)(B0 + (kc2 * 4 + nt) * 1024 + lane * 16);
            acc[nt] = MFMA32(w, de[kc2], acc[nt], 0, 0, 0);
        }
    SP0;

    // ---- c1 bias+relu, color2 dots, sigmoid; all stores here ----
    float rr0 = 0.f, rr1 = 0.f, rr2 = 0.f;
#pragma unroll
    for (int nt = 0; nt < 4; ++nt) {
        float c1v[16];
#pragma unroll
        for (int q = 0; q < 4; ++q) {
            const f32x4 b4 = *(const f32x4*)(biasL + ((2048 + nt * 32 + q * 8 + h4) << 2));
#pragma unroll
            for (int i2 = 0; i2 < 4; ++i2)
                c1v[q * 4 + i2] = fmaxf(acc[nt][q * 4 + i2] + b4[i2], 0.f);
        }
        const long wb = (long)(OFF_WC2 + nt * 32 + h16) * 2;
        const s8 w0a = *(const s8*)(wsB + wb);
        const s8 w0b = *(const s8*)(wsB + wb + 16);
        const s8 w1a = *(const s8*)(wsB + wb + 256);
        const s8 w1b = *(const s8*)(wsB + wb + 272);
        const s8 w2a = *(const s8*)(wsB + wb + 512);
        const s8 w2b = *(const s8*)(wsB + wb + 528);
#pragma unroll
        for (int r = 0; r < 8; ++r) {
            rr0 += c1v[r] * bf2f(w0a[r]) + c1v[8 + r] * bf2f(w0b[r]);
            rr1 += c1v[r] * bf2f(w1a[r]) + c1v[8 + r] * bf2f(w1b[r]);
            rr2 += c1v[r] * bf2f(w2a[r]) + c1v[8 + r] * bf2f(w2b[r]);
        }
    }
    rr0 += __shfl_xor(rr0, 32);
    rr1 += __shfl_xor(rr1, 32);
    rr2 += __shfl_xor(rr2, 32);
    if (lane < 32) {
        out[g * 3 + 0] = 1.f / (1.f + __expf(-(rr0 + b_c2[0])));
        out[g * 3 + 1] = 1.f / (1.f + __expf(-(rr1 + b_c2[1])));
        out[g * 3 + 2] = 1.f / (1.f + __expf(-(rr2 + b_c2[2])));
        out[3 * N_PTS + g] = alpha;
    }
}

extern "C" void kernel_launch(void* const* d_in, const int* in_sizes, int n_in,
                              void* d_out, int out_size, void* d_ws, size_t ws_size,
                              hipStream_t stream) {
    const float* position = (const float*)d_in[0];
    const float* direction = (const float*)d_in[1];
    const float* w1_in = (const float*)d_in[2];
    const float* b1_in = (const float*)d_in[3];
    const float* w1_h  = (const float*)d_in[4];
    const float* b1_h  = (const float*)d_in[5];
    const float* w2_in = (const float*)d_in[6];
    const float* b2_in = (const float*)d_in[7];
    const float* w2_h  = (const float*)d_in[8];
    const float* b2_h  = (const float*)d_in[9];
    const float* w_sigma = (const float*)d_in[10];
    const float* b_sigma = (const float*)d_in[11];
    const float* w_c1  = (const float*)d_in[12];
    const float* b_c1  = (const float*)d_in[13];
    const float* w_c2  = (const float*)d_in[14];
    const float* b_c2  = (const float*)d_in[15];
    float* out = (float*)d_out;
    __hip_bfloat16* ws = (__hip_bfloat16*)d_ws;

    prep_weights<<<(WS_ELEMS + 255) / 256, 256, 0, stream>>>(
        w1_in, w1_h, w2_in, w2_h, w_c1, w_sigma, w_c2, ws);

    nerf_fused<<<N_PTS / 128, 256, 0, stream>>>(
        position, direction, ws,
        b1_in, b1_h, b2_in, b2_h,
        b_sigma, b_c1, b_c2, out);
}